// Round 1
// baseline (558.140 us; speedup 1.0000x reference)
//
#include <hip/hip_runtime.h>

// Problem constants (fixed by setup_inputs)
constexpr int N  = 4096;   // H*W
constexpr int C  = 512;
constexpr int CK = 64;     // C/8
constexpr int B  = 4;

// ---------------------------------------------------------------------------
// Kernel 1: f = Wq @ x, g = Wk @ x   →  fg[b][row][i], rows 0..63 = f, 64..127 = g
// Tile: 128 rows x 64 cols per block; micro-tile 8x4 per thread (256 threads).
// ---------------------------------------------------------------------------
__global__ __launch_bounds__(256, 2)
void proj_fg(const float* __restrict__ x, const float* __restrict__ Wq,
             const float* __restrict__ Wk, float* __restrict__ fg)
{
    int b  = blockIdx.y;
    int i0 = blockIdx.x * 64;
    __shared__ __align__(16) float xs[16][64];
    __shared__ __align__(16) float ws[16][132];   // wsT[cc][row], padded
    int tid = threadIdx.x, ty = tid >> 4, tx = tid & 15;
    float acc[8][4] = {};
    const float* xb = x + (size_t)b * C * N;

    for (int c0 = 0; c0 < C; c0 += 16) {
        // stage x tile: 16 x 64 floats, one float4 per thread, coalesced over i
        {
            int cc = tid >> 4, col4 = (tid & 15) * 4;
            *(float4*)&xs[cc][col4] =
                *(const float4*)&xb[(size_t)(c0 + cc) * N + i0 + col4];
        }
        // stage W tile transposed: ws[cc][row]
        for (int v = tid; v < 2048; v += 256) {
            int row = v >> 4, cc = v & 15;
            ws[cc][row] = (row < 64) ? Wq[row * C + c0 + cc]
                                     : Wk[(row - 64) * C + c0 + cc];
        }
        __syncthreads();
        #pragma unroll
        for (int cc = 0; cc < 16; ++cc) {
            float4 wa = *(const float4*)&ws[cc][ty * 4];
            float4 wb = *(const float4*)&ws[cc][64 + ty * 4];
            float4 xa = *(const float4*)&xs[cc][tx * 4];
            float wr[8] = {wa.x, wa.y, wa.z, wa.w, wb.x, wb.y, wb.z, wb.w};
            float xc[4] = {xa.x, xa.y, xa.z, xa.w};
            #pragma unroll
            for (int r = 0; r < 8; ++r)
                #pragma unroll
                for (int cl = 0; cl < 4; ++cl)
                    acc[r][cl] += wr[r] * xc[cl];
        }
        __syncthreads();
    }
    float* outb = fg + (size_t)b * 128 * N;
    #pragma unroll
    for (int r = 0; r < 8; ++r) {
        int row = (r < 4) ? (ty * 4 + r) : (64 + ty * 4 + (r - 4));
        *(float4*)&outb[(size_t)row * N + i0 + tx * 4] =
            make_float4(acc[r][0], acc[r][1], acc[r][2], acc[r][3]);
    }
}

// ---------------------------------------------------------------------------
// Kernel 2: scores[i,j] = sum_k f[k,i]*g[k,j]; p = exp(scores - 20); store p
// (unnormalized) into beta region; atomically accumulate column sums l[b,j].
// Tile: 128x128 per block (K=64 staged entirely in LDS), 8x8 micro-tile.
// ---------------------------------------------------------------------------
__global__ __launch_bounds__(256, 2)
void scores_exp(const float* __restrict__ fg, float* __restrict__ p,
                float* __restrict__ colsum)
{
    int b  = blockIdx.z;
    int i0 = blockIdx.y * 128;
    int j0 = blockIdx.x * 128;
    __shared__ __align__(16) float fs[CK][128];   // 32 KB
    __shared__ __align__(16) float gs[CK][128];   // 32 KB
    int tid = threadIdx.x, ty = tid >> 4, tx = tid & 15;
    const float* fb = fg + (size_t)b * 128 * N;       // f: rows 0..63
    const float* gb = fb + (size_t)64 * N;            // g: rows 64..127

    for (int v = tid; v < CK * 32; v += 256) {        // 2048 float4 pairs
        int k = v >> 5, col4 = (v & 31) * 4;
        *(float4*)&fs[k][col4] = *(const float4*)&fb[(size_t)k * N + i0 + col4];
        *(float4*)&gs[k][col4] = *(const float4*)&gb[(size_t)k * N + j0 + col4];
    }
    __syncthreads();

    float acc[8][8] = {};
    #pragma unroll 4
    for (int k = 0; k < CK; ++k) {
        float4 fa  = *(const float4*)&fs[k][ty * 4];
        float4 fb4 = *(const float4*)&fs[k][64 + ty * 4];
        float4 ga  = *(const float4*)&gs[k][tx * 4];
        float4 gb4 = *(const float4*)&gs[k][64 + tx * 4];
        float fr[8] = {fa.x, fa.y, fa.z, fa.w, fb4.x, fb4.y, fb4.z, fb4.w};
        float gc[8] = {ga.x, ga.y, ga.z, ga.w, gb4.x, gb4.y, gb4.z, gb4.w};
        #pragma unroll
        for (int r = 0; r < 8; ++r)
            #pragma unroll
            for (int cl = 0; cl < 8; ++cl)
                acc[r][cl] += fr[r] * gc[cl];
    }

    // exp + store unnormalized p + per-thread column partials
    float cs[8] = {};
    float* pb = p + (size_t)b * N * N;
    #pragma unroll
    for (int r = 0; r < 8; ++r) {
        int i = i0 + ((r < 4) ? (ty * 4 + r) : (64 + ty * 4 + (r - 4)));
        float4 v0, v1;
        float e;
        e = __expf(acc[r][0] - 20.0f); v0.x = e; cs[0] += e;
        e = __expf(acc[r][1] - 20.0f); v0.y = e; cs[1] += e;
        e = __expf(acc[r][2] - 20.0f); v0.z = e; cs[2] += e;
        e = __expf(acc[r][3] - 20.0f); v0.w = e; cs[3] += e;
        e = __expf(acc[r][4] - 20.0f); v1.x = e; cs[4] += e;
        e = __expf(acc[r][5] - 20.0f); v1.y = e; cs[5] += e;
        e = __expf(acc[r][6] - 20.0f); v1.z = e; cs[6] += e;
        e = __expf(acc[r][7] - 20.0f); v1.w = e; cs[7] += e;
        *(float4*)&pb[(size_t)i * N + j0 + tx * 4]      = v0;
        *(float4*)&pb[(size_t)i * N + j0 + 64 + tx * 4] = v1;
    }

    // block-level column-sum reduction (reuse fs as scratch), then atomicAdd
    __syncthreads();
    float* red = (float*)fs;   // need 16*128 floats
    #pragma unroll
    for (int e2 = 0; e2 < 4; ++e2) {
        red[ty * 128 + tx * 4 + e2]      = cs[e2];
        red[ty * 128 + 64 + tx * 4 + e2] = cs[4 + e2];
    }
    __syncthreads();
    if (tid < 128) {
        float s = 0.f;
        #pragma unroll
        for (int t2 = 0; t2 < 16; ++t2) s += red[t2 * 128 + tid];
        atomicAdd(&colsum[(size_t)b * N + j0 + tid], s);
    }
}

// ---------------------------------------------------------------------------
// Kernel 3: beta = p / l[b,j] in place; rowsum[b,i] = sum_j beta[b,i,j].
// One block per (b, i) row — no atomics needed for rowsum.
// ---------------------------------------------------------------------------
__global__ __launch_bounds__(256)
void normalize_rowsum(float* __restrict__ p, const float* __restrict__ colsum,
                      float* __restrict__ rowsum)
{
    int b = blockIdx.y, i = blockIdx.x, tid = threadIdx.x;
    float* row      = p + ((size_t)b * N + i) * N;
    const float* l  = colsum + (size_t)b * N;
    float rs = 0.f;
    for (int base = 0; base < N; base += 1024) {
        int j = base + tid * 4;
        float4 v  = *(const float4*)&row[j];
        float4 li = *(const float4*)&l[j];
        v.x /= li.x; v.y /= li.y; v.z /= li.z; v.w /= li.w;
        rs += v.x + v.y + v.z + v.w;
        *(float4*)&row[j] = v;
    }
    __shared__ float sred[256];
    sred[tid] = rs;
    __syncthreads();
    for (int s = 128; s > 0; s >>= 1) {
        if (tid < s) sred[tid] += sred[tid + s];
        __syncthreads();
    }
    if (tid == 0) rowsum[(size_t)b * N + i] = sred[0];
}

// ---------------------------------------------------------------------------
// Kernel 4: meanx[b,c] = (1/N) sum_i x[b,c,i];  t[b,c] = sum_i x[b,c,i]*r[b,i]
// ---------------------------------------------------------------------------
__global__ __launch_bounds__(256)
void reduce_xr(const float* __restrict__ x, const float* __restrict__ rowsum,
               float* __restrict__ meanx, float* __restrict__ tvec)
{
    int b = blockIdx.y, c = blockIdx.x, tid = threadIdx.x;
    const float* xr = x + ((size_t)b * C + c) * N;
    const float* rr = rowsum + (size_t)b * N;
    float sx = 0.f, st = 0.f;
    for (int base = 0; base < N; base += 1024) {
        int i = base + tid * 4;
        float4 xv = *(const float4*)&xr[i];
        float4 rv = *(const float4*)&rr[i];
        sx += xv.x + xv.y + xv.z + xv.w;
        st += xv.x * rv.x + xv.y * rv.y + xv.z * rv.z + xv.w * rv.w;
    }
    __shared__ float s1[256], s2[256];
    s1[tid] = sx; s2[tid] = st;
    __syncthreads();
    for (int s = 128; s > 0; s >>= 1) {
        if (tid < s) { s1[tid] += s1[tid + s]; s2[tid] += s2[tid + s]; }
        __syncthreads();
    }
    if (tid == 0) {
        meanx[b * C + c] = s1[0] * (1.0f / N);
        tvec [b * C + c] = s2[0];
    }
}

// ---------------------------------------------------------------------------
// Kernel 5: pooled[b,c] = meanx[b,c] + (gamma/N) * sum_c' Wv[c,c'] * t[b,c']
// One wave per (b,c).
// ---------------------------------------------------------------------------
__global__ __launch_bounds__(64)
void pooled_out(const float* __restrict__ Wv, const float* __restrict__ meanx,
                const float* __restrict__ tvec, const float* __restrict__ gamma,
                float* __restrict__ out)
{
    int b = blockIdx.y, c = blockIdx.x;
    const float* wr = Wv + (size_t)c * C;
    const float* t  = tvec + (size_t)b * C;
    float s = 0.f;
    for (int cc = threadIdx.x; cc < C; cc += 64) s += wr[cc] * t[cc];
    for (int off = 32; off > 0; off >>= 1) s += __shfl_down(s, off);
    if (threadIdx.x == 0)
        out[b * C + c] = meanx[b * C + c] + gamma[0] * (1.0f / N) * s;
}

// ---------------------------------------------------------------------------
extern "C" void kernel_launch(void* const* d_in, const int* in_sizes, int n_in,
                              void* d_out, int out_size, void* d_ws, size_t ws_size,
                              hipStream_t stream)
{
    const float* x     = (const float*)d_in[0];
    const float* Wq    = (const float*)d_in[1];
    const float* Wk    = (const float*)d_in[2];
    const float* Wv    = (const float*)d_in[3];
    const float* gamma = (const float*)d_in[4];
    float* out  = (float*)d_out;
    float* beta = out + (size_t)B * C;            // pooled is B*C = 2048 floats

    // workspace layout (floats)
    float* fg     = (float*)d_ws;                 // B*128*N   = 2,097,152
    float* colsum = fg + (size_t)B * 128 * N;     // B*N       = 16,384
    float* rowsum = colsum + (size_t)B * N;       // B*N       = 16,384
    float* meanx  = rowsum + (size_t)B * N;       // B*C       = 2,048
    float* tvec   = meanx + (size_t)B * C;        // B*C       = 2,048

    hipMemsetAsync(colsum, 0, (size_t)B * N * sizeof(float), stream);

    proj_fg        <<<dim3(N / 64, B),        256, 0, stream>>>(x, Wq, Wk, fg);
    scores_exp     <<<dim3(N / 128, N / 128, B), 256, 0, stream>>>(fg, beta, colsum);
    normalize_rowsum<<<dim3(N, B),            256, 0, stream>>>(beta, colsum, rowsum);
    reduce_xr      <<<dim3(C, B),             256, 0, stream>>>(x, rowsum, meanx, tvec);
    pooled_out     <<<dim3(C, B),              64, 0, stream>>>(Wv, meanx, tvec, gamma, out);
}

// Round 2
// 470.784 us; speedup vs baseline: 1.1856x; 1.1856x over previous
//
#include <hip/hip_runtime.h>

constexpr int N  = 4096;   // H*W
constexpr int C  = 512;
constexpr int CK = 64;     // C/8
constexpr int B  = 4;

typedef __attribute__((ext_vector_type(8))) short short8;
typedef __attribute__((ext_vector_type(4))) float f32x4;

// ---------------------------------------------------------------------------
// Kernel 1: f = Wq @ x, g = Wk @ x  → fg[b][row][i] fp32, rows 0..63=f, 64..127=g
// ---------------------------------------------------------------------------
__global__ __launch_bounds__(256, 2)
void proj_fg(const float* __restrict__ x, const float* __restrict__ Wq,
             const float* __restrict__ Wk, float* __restrict__ fg)
{
    int b  = blockIdx.y;
    int i0 = blockIdx.x * 64;
    __shared__ __align__(16) float xs[16][64];
    __shared__ __align__(16) float ws[16][132];
    int tid = threadIdx.x, ty = tid >> 4, tx = tid & 15;
    float acc[8][4] = {};
    const float* xb = x + (size_t)b * C * N;

    for (int c0 = 0; c0 < C; c0 += 16) {
        {
            int cc = tid >> 4, col4 = (tid & 15) * 4;
            *(float4*)&xs[cc][col4] =
                *(const float4*)&xb[(size_t)(c0 + cc) * N + i0 + col4];
        }
        for (int v = tid; v < 2048; v += 256) {
            int row = v >> 4, cc = v & 15;
            ws[cc][row] = (row < 64) ? Wq[row * C + c0 + cc]
                                     : Wk[(row - 64) * C + c0 + cc];
        }
        __syncthreads();
        #pragma unroll
        for (int cc = 0; cc < 16; ++cc) {
            float4 wa = *(const float4*)&ws[cc][ty * 4];
            float4 wb = *(const float4*)&ws[cc][64 + ty * 4];
            float4 xa = *(const float4*)&xs[cc][tx * 4];
            float wr[8] = {wa.x, wa.y, wa.z, wa.w, wb.x, wb.y, wb.z, wb.w};
            float xc[4] = {xa.x, xa.y, xa.z, xa.w};
            #pragma unroll
            for (int r = 0; r < 8; ++r)
                #pragma unroll
                for (int cl = 0; cl < 4; ++cl)
                    acc[r][cl] += wr[r] * xc[cl];
        }
        __syncthreads();
    }
    float* outb = fg + (size_t)b * 128 * N;
    #pragma unroll
    for (int r = 0; r < 8; ++r) {
        int row = (r < 4) ? (ty * 4 + r) : (64 + ty * 4 + (r - 4));
        *(float4*)&outb[(size_t)row * N + i0 + tx * 4] =
            make_float4(acc[r][0], acc[r][1], acc[r][2], acc[r][3]);
    }
}

// ---------------------------------------------------------------------------
// Kernel 2: transpose fg [k][i] fp32 → fT/gT [i][k] bf16 hi/lo split.
// half=0 → f rows 0..63; half=1 → g rows 64..127.
// ---------------------------------------------------------------------------
__global__ __launch_bounds__(256)
void transpose_split(const float* __restrict__ fg,
                     ushort* __restrict__ fT_hi, ushort* __restrict__ fT_lo,
                     ushort* __restrict__ gT_hi, ushort* __restrict__ gT_lo)
{
    int b = blockIdx.z, half = blockIdx.y, i0 = blockIdx.x * 64;
    const float* src = fg + ((size_t)b * 128 + half * 64) * N;
    __shared__ float tile[64][68];
    int t = threadIdx.x;
    {
        int k = t >> 2, ic = (t & 3) * 16;
        #pragma unroll
        for (int c4 = 0; c4 < 16; c4 += 4)
            *(float4*)&tile[k][ic + c4] =
                *(const float4*)&src[(size_t)k * N + i0 + ic + c4];
    }
    __syncthreads();
    int i = t >> 2, kc = (t & 3) * 16;
    ushort hi[16], lo[16];
    #pragma unroll
    for (int kk = 0; kk < 16; ++kk) {
        float v = tile[kc + kk][i];
        unsigned bits = __float_as_uint(v);
        unsigned hb   = bits & 0xFFFF0000u;
        hi[kk] = (ushort)(hb >> 16);
        float lof = v - __uint_as_float(hb);
        lo[kk] = (ushort)(__float_as_uint(lof) >> 16);
    }
    size_t ofs = ((size_t)b * N + i0 + i) * 64 + kc;
    ushort* dh = (half ? gT_hi : fT_hi) + ofs;
    ushort* dl = (half ? gT_lo : fT_lo) + ofs;
    ((uint4*)dh)[0] = ((uint4*)hi)[0]; ((uint4*)dh)[1] = ((uint4*)hi)[1];
    ((uint4*)dl)[0] = ((uint4*)lo)[0]; ((uint4*)dl)[1] = ((uint4*)lo)[1];
}

// ---------------------------------------------------------------------------
// Kernels 3/5: MFMA scores + exp. PASS=1: colsum only. PASS=2: write beta
// (scaled by inv colsum) + rowsum atomics.
// 128x128 tile, 4 waves × (32 rows × 128 cols), hi/lo split = 3 products.
// ---------------------------------------------------------------------------
template <int PASS>
__global__ __launch_bounds__(256, 2)
void scores_pass(const ushort* __restrict__ fT_hi, const ushort* __restrict__ fT_lo,
                 const ushort* __restrict__ gT_hi, const ushort* __restrict__ gT_lo,
                 const float* __restrict__ inv_l, float* __restrict__ colsum,
                 float* __restrict__ beta, float* __restrict__ rowsum)
{
    int b = blockIdx.z, i0 = blockIdx.y * 128, j0 = blockIdx.x * 128;
    __shared__ ushort sm[4][128][72];   // 73.7 KB, pad 8 → 2-way-free banks
    int tid = threadIdx.x;

    const ushort* fh = fT_hi + ((size_t)b * N + i0) * 64;
    const ushort* fl = fT_lo + ((size_t)b * N + i0) * 64;
    const ushort* gh = gT_hi + ((size_t)b * N + j0) * 64;
    const ushort* gl = gT_lo + ((size_t)b * N + j0) * 64;
    #pragma unroll
    for (int v = tid; v < 1024; v += 256) {
        int row = v >> 3, ch = (v & 7) * 8;
        *(uint4*)&sm[0][row][ch] = *(const uint4*)&fh[(size_t)row * 64 + ch];
        *(uint4*)&sm[1][row][ch] = *(const uint4*)&fl[(size_t)row * 64 + ch];
        *(uint4*)&sm[2][row][ch] = *(const uint4*)&gh[(size_t)row * 64 + ch];
        *(uint4*)&sm[3][row][ch] = *(const uint4*)&gl[(size_t)row * 64 + ch];
    }
    __syncthreads();

    int w = tid >> 6, lane = tid & 63, l15 = lane & 15, quad = lane >> 4;
    f32x4 acc[2][8] = {};

    const int pA[3] = {0, 0, 1};   // f_hi, f_hi, f_lo
    const int pB[3] = {2, 3, 2};   // g_hi, g_lo, g_hi
    #pragma unroll
    for (int p = 0; p < 3; ++p) {
        #pragma unroll
        for (int ks = 0; ks < 2; ++ks) {
            int kofs = ks * 32 + quad * 8;
            short8 afr[2];
            #pragma unroll
            for (int tr = 0; tr < 2; ++tr)
                afr[tr] = *(const short8*)&sm[pA[p]][w * 32 + tr * 16 + l15][kofs];
            #pragma unroll
            for (int tc = 0; tc < 8; ++tc) {
                short8 bfr = *(const short8*)&sm[pB[p]][tc * 16 + l15][kofs];
                acc[0][tc] = __builtin_amdgcn_mfma_f32_16x16x32_bf16(afr[0], bfr, acc[0][tc], 0, 0, 0);
                acc[1][tc] = __builtin_amdgcn_mfma_f32_16x16x32_bf16(afr[1], bfr, acc[1][tc], 0, 0, 0);
            }
        }
    }

    if (PASS == 1) {
        float cs[8];
        #pragma unroll
        for (int tc = 0; tc < 8; ++tc) cs[tc] = 0.f;
        #pragma unroll
        for (int tr = 0; tr < 2; ++tr)
            #pragma unroll
            for (int tc = 0; tc < 8; ++tc)
                #pragma unroll
                for (int r = 0; r < 4; ++r)
                    cs[tc] += __expf(acc[tr][tc][r] - 20.0f);
        __syncthreads();
        float* red = (float*)&sm[0][0][0];   // 128 j × 17 slots
        #pragma unroll
        for (int tc = 0; tc < 8; ++tc)
            red[(tc * 16 + l15) * 17 + (w * 4 + quad)] = cs[tc];
        __syncthreads();
        if (tid < 128) {
            float s = 0.f;
            #pragma unroll
            for (int sl = 0; sl < 16; ++sl) s += red[tid * 17 + sl];
            atomicAdd(&colsum[(size_t)b * N + j0 + tid], s);
        }
    } else {
        float il[8];
        #pragma unroll
        for (int tc = 0; tc < 8; ++tc)
            il[tc] = inv_l[(size_t)b * N + j0 + tc * 16 + l15];
        float* pb = beta + (size_t)b * N * N;
        #pragma unroll
        for (int tr = 0; tr < 2; ++tr) {
            float rp[4] = {0.f, 0.f, 0.f, 0.f};
            #pragma unroll
            for (int tc = 0; tc < 8; ++tc) {
                int j = j0 + tc * 16 + l15;
                #pragma unroll
                for (int r = 0; r < 4; ++r) {
                    int i = i0 + w * 32 + tr * 16 + quad * 4 + r;
                    float v = __expf(acc[tr][tc][r] - 20.0f) * il[tc];
                    rp[r] += v;
                    pb[(size_t)i * N + j] = v;
                }
            }
            #pragma unroll
            for (int r = 0; r < 4; ++r) {
                float s = rp[r];
                s += __shfl_xor(s, 1); s += __shfl_xor(s, 2);
                s += __shfl_xor(s, 4); s += __shfl_xor(s, 8);
                if (l15 == 0)
                    atomicAdd(&rowsum[(size_t)b * N + i0 + w * 32 + tr * 16 + quad * 4 + r], s);
            }
        }
    }
}

// ---------------------------------------------------------------------------
// Kernel 4: in-place invert colsum
// ---------------------------------------------------------------------------
__global__ __launch_bounds__(256)
void invert_colsum(float* __restrict__ c)
{
    int t = blockIdx.x * 256 + threadIdx.x;
    c[t] = 1.0f / c[t];
}

// ---------------------------------------------------------------------------
// Kernel 6: meanx[b,c] = mean_i x; t[b,c] = sum_i x[b,c,i]*rowsum[b,i]
// ---------------------------------------------------------------------------
__global__ __launch_bounds__(256)
void reduce_xr(const float* __restrict__ x, const float* __restrict__ rowsum,
               float* __restrict__ meanx, float* __restrict__ tvec)
{
    int b = blockIdx.y, c = blockIdx.x, tid = threadIdx.x;
    const float* xr = x + ((size_t)b * C + c) * N;
    const float* rr = rowsum + (size_t)b * N;
    float sx = 0.f, st = 0.f;
    for (int base = 0; base < N; base += 1024) {
        int i = base + tid * 4;
        float4 xv = *(const float4*)&xr[i];
        float4 rv = *(const float4*)&rr[i];
        sx += xv.x + xv.y + xv.z + xv.w;
        st += xv.x * rv.x + xv.y * rv.y + xv.z * rv.z + xv.w * rv.w;
    }
    __shared__ float s1[256], s2[256];
    s1[tid] = sx; s2[tid] = st;
    __syncthreads();
    for (int s = 128; s > 0; s >>= 1) {
        if (tid < s) { s1[tid] += s1[tid + s]; s2[tid] += s2[tid + s]; }
        __syncthreads();
    }
    if (tid == 0) {
        meanx[b * C + c] = s1[0] * (1.0f / N);
        tvec [b * C + c] = s2[0];
    }
}

// ---------------------------------------------------------------------------
// Kernel 7: pooled[b,c] = meanx + (gamma/N) * sum_c' Wv[c,c'] * t[b,c']
// ---------------------------------------------------------------------------
__global__ __launch_bounds__(64)
void pooled_out(const float* __restrict__ Wv, const float* __restrict__ meanx,
                const float* __restrict__ tvec, const float* __restrict__ gamma,
                float* __restrict__ out)
{
    int b = blockIdx.y, c = blockIdx.x;
    const float* wr = Wv + (size_t)c * C;
    const float* t  = tvec + (size_t)b * C;
    float s = 0.f;
    for (int cc = threadIdx.x; cc < C; cc += 64) s += wr[cc] * t[cc];
    for (int off = 32; off > 0; off >>= 1) s += __shfl_down(s, off);
    if (threadIdx.x == 0)
        out[b * C + c] = meanx[b * C + c] + gamma[0] * (1.0f / N) * s;
}

// ---------------------------------------------------------------------------
extern "C" void kernel_launch(void* const* d_in, const int* in_sizes, int n_in,
                              void* d_out, int out_size, void* d_ws, size_t ws_size,
                              hipStream_t stream)
{
    const float* x     = (const float*)d_in[0];
    const float* Wq    = (const float*)d_in[1];
    const float* Wk    = (const float*)d_in[2];
    const float* Wv    = (const float*)d_in[3];
    const float* gamma = (const float*)d_in[4];
    float* out  = (float*)d_out;
    float* beta = out + (size_t)B * C;

    // workspace layout
    float*  fg    = (float*)d_ws;                         // B*128*N fp32
    ushort* ubase = (ushort*)(fg + (size_t)B * 128 * N);
    ushort* fT_hi = ubase;                                // each B*N*64 ushort
    ushort* fT_lo = fT_hi + (size_t)B * N * 64;
    ushort* gT_hi = fT_lo + (size_t)B * N * 64;
    ushort* gT_lo = gT_hi + (size_t)B * N * 64;
    float*  colsum = (float*)(gT_lo + (size_t)B * N * 64); // B*N
    float*  rowsum = colsum + (size_t)B * N;               // B*N
    float*  meanx  = rowsum + (size_t)B * N;               // B*C
    float*  tvec   = meanx + (size_t)B * C;                // B*C

    hipMemsetAsync(colsum, 0, 2 * (size_t)B * N * sizeof(float), stream);

    proj_fg        <<<dim3(N / 64, B),           256, 0, stream>>>(x, Wq, Wk, fg);
    transpose_split<<<dim3(N / 64, 2, B),        256, 0, stream>>>(fg, fT_hi, fT_lo, gT_hi, gT_lo);
    scores_pass<1> <<<dim3(N / 128, N / 128, B), 256, 0, stream>>>(fT_hi, fT_lo, gT_hi, gT_lo,
                                                                   colsum, colsum, beta, rowsum);
    invert_colsum  <<<dim3(B * N / 256),         256, 0, stream>>>(colsum);
    scores_pass<2> <<<dim3(N / 128, N / 128, B), 256, 0, stream>>>(fT_hi, fT_lo, gT_hi, gT_lo,
                                                                   colsum, colsum, beta, rowsum);
    reduce_xr      <<<dim3(C, B),                256, 0, stream>>>(x, rowsum, meanx, tvec);
    pooled_out     <<<dim3(C, B),                 64, 0, stream>>>(Wv, meanx, tvec, gamma, out);
}